// Round 1
// baseline (259.389 us; speedup 1.0000x reference)
//
#include <hip/hip_runtime.h>
#include <math.h>

#define NB 8
#define LQ 2048
#define LK 2048
#define DIN 1024
#define DQK 128
#define DV 128
#define MROWS (NB * LQ)   // 16384

static constexpr float KSCALE = 0.022097086912079608f; // 1/sqrt(2048)

// ---------------------------------------------------------------------------
// Kernel 1: Y[16384][128] = relu(X[16384][1024] @ W[1024][128] + bias)
// blockIdx.y in {0,1,2} selects (query,Wq,bq)->qp, (key,Wk,bk)->kp, (value,Wv,bv)->vp
// Tile: 64 rows x 128 cols per block, 256 threads, thread = 8 rows x 4 cols.
// ---------------------------------------------------------------------------
__global__ __launch_bounds__(256) void proj_kernel(
    const float* __restrict__ Xq, const float* __restrict__ Wq, const float* __restrict__ bq,
    const float* __restrict__ Xk, const float* __restrict__ Wk, const float* __restrict__ bk,
    const float* __restrict__ Xv, const float* __restrict__ Wv, const float* __restrict__ bv,
    float* __restrict__ Yq, float* __restrict__ Yk, float* __restrict__ Yv)
{
    const float* X; const float* W; const float* bias; float* Y;
    if (blockIdx.y == 0)      { X = Xq; W = Wq; bias = bq; Y = Yq; }
    else if (blockIdx.y == 1) { X = Xk; W = Wk; bias = bk; Y = Yk; }
    else                      { X = Xv; W = Wv; bias = bv; Y = Yv; }

    const int tid  = threadIdx.x;
    const int row0 = blockIdx.x * 64;

    // Xs transposed [k][row], stride 68 floats (272B, 16B-aligned rows, spreads banks)
    __shared__ __align__(16) float Xs[16][68];
    __shared__ __align__(16) float Ws[16][128];

    const int trow = tid >> 5;        // 0..7
    const int tcol = tid & 31;        // 0..31
    const int r0   = trow * 8;        // thread's 8 rows in tile
    const int c0   = tcol * 4;        // thread's 4 cols

    // X staging mapping: thread reads X[row0 + (tid>>2)][kc + (tid&3)*4 .. +3]
    const int lxr = tid >> 2;         // 0..63
    const int lxk = (tid & 3) * 4;    // 0,4,8,12
    // W staging: thread reads rows (tid>>5) and (tid>>5)+8 of the k-chunk
    const int lwk = tid >> 5;         // 0..7
    const int lwc = (tid & 31) * 4;   // 0..124

    float acc[8][4];
    #pragma unroll
    for (int i = 0; i < 8; ++i)
        #pragma unroll
        for (int j = 0; j < 4; ++j) acc[i][j] = 0.f;

    for (int kc = 0; kc < DIN; kc += 16) {
        float4 xv  = *(const float4*)&X[(size_t)(row0 + lxr) * DIN + kc + lxk];
        float4 wv0 = *(const float4*)&W[(size_t)(kc + lwk) * 128 + lwc];
        float4 wv1 = *(const float4*)&W[(size_t)(kc + 8 + lwk) * 128 + lwc];
        __syncthreads();   // previous iteration's compute reads done
        Xs[lxk + 0][lxr] = xv.x;
        Xs[lxk + 1][lxr] = xv.y;
        Xs[lxk + 2][lxr] = xv.z;
        Xs[lxk + 3][lxr] = xv.w;
        *(float4*)&Ws[lwk][lwc]     = wv0;
        *(float4*)&Ws[lwk + 8][lwc] = wv1;
        __syncthreads();
        #pragma unroll
        for (int kk = 0; kk < 16; ++kk) {
            float4 a0 = *(const float4*)&Xs[kk][r0];
            float4 a1 = *(const float4*)&Xs[kk][r0 + 4];
            float4 bb = *(const float4*)&Ws[kk][c0];
            float a[8] = {a0.x, a0.y, a0.z, a0.w, a1.x, a1.y, a1.z, a1.w};
            float bv4[4] = {bb.x, bb.y, bb.z, bb.w};
            #pragma unroll
            for (int i = 0; i < 8; ++i)
                #pragma unroll
                for (int j = 0; j < 4; ++j)
                    acc[i][j] = fmaf(a[i], bv4[j], acc[i][j]);
        }
    }

    const float4 bvec = *(const float4*)&bias[c0];
    #pragma unroll
    for (int i = 0; i < 8; ++i) {
        float4 o;
        o.x = fmaxf(acc[i][0] + bvec.x, 0.f);
        o.y = fmaxf(acc[i][1] + bvec.y, 0.f);
        o.z = fmaxf(acc[i][2] + bvec.z, 0.f);
        o.w = fmaxf(acc[i][3] + bvec.w, 0.f);
        *(float4*)&Y[(size_t)(row0 + r0 + i) * 128 + c0] = o;
    }
}

// ---------------------------------------------------------------------------
// Kernel 2: M[b][e][v] += KSCALE * sum_r kp[b][r][e] * vp[b][r][v]
// grid = (16 row-chunks of 128, 8 batches); 256 threads; thread = 8e x 8v.
// M must be zeroed before launch (atomicAdd accumulation across chunks).
// ---------------------------------------------------------------------------
__global__ __launch_bounds__(256) void ktv_kernel(
    const float* __restrict__ kp, const float* __restrict__ vp, float* __restrict__ M)
{
    const int batch = blockIdx.y;
    const int rbase = blockIdx.x * 128;
    const float* K = kp + (size_t)batch * LK * DQK + (size_t)rbase * DQK;
    const float* V = vp + (size_t)batch * LK * DV  + (size_t)rbase * DV;
    float* Mb = M + (size_t)batch * DQK * DV;

    __shared__ __align__(16) float ks[16][128];
    __shared__ __align__(16) float vs[16][128];

    const int tid = threadIdx.x;
    const int e0  = (tid >> 4) * 8;   // 0..120
    const int v0  = (tid & 15) * 8;   // 0..120

    const int lr = tid >> 5;          // 0..7
    const int lc = (tid & 31) * 4;    // 0..124

    float acc[8][8];
    #pragma unroll
    for (int i = 0; i < 8; ++i)
        #pragma unroll
        for (int j = 0; j < 8; ++j) acc[i][j] = 0.f;

    for (int rc = 0; rc < 128; rc += 16) {
        float4 k0 = *(const float4*)&K[(size_t)(rc + lr) * 128 + lc];
        float4 k1 = *(const float4*)&K[(size_t)(rc + 8 + lr) * 128 + lc];
        float4 v0g = *(const float4*)&V[(size_t)(rc + lr) * 128 + lc];
        float4 v1g = *(const float4*)&V[(size_t)(rc + 8 + lr) * 128 + lc];
        __syncthreads();
        *(float4*)&ks[lr][lc]     = k0;
        *(float4*)&ks[lr + 8][lc] = k1;
        *(float4*)&vs[lr][lc]     = v0g;
        *(float4*)&vs[lr + 8][lc] = v1g;
        __syncthreads();
        #pragma unroll
        for (int rr = 0; rr < 16; ++rr) {
            float4 a0 = *(const float4*)&ks[rr][e0];
            float4 a1 = *(const float4*)&ks[rr][e0 + 4];
            float4 b0 = *(const float4*)&vs[rr][v0];
            float4 b1 = *(const float4*)&vs[rr][v0 + 4];
            float a[8] = {a0.x, a0.y, a0.z, a0.w, a1.x, a1.y, a1.z, a1.w};
            float b[8] = {b0.x, b0.y, b0.z, b0.w, b1.x, b1.y, b1.z, b1.w};
            #pragma unroll
            for (int i = 0; i < 8; ++i)
                #pragma unroll
                for (int j = 0; j < 8; ++j)
                    acc[i][j] = fmaf(a[i], b[j], acc[i][j]);
        }
    }

    #pragma unroll
    for (int i = 0; i < 8; ++i)
        #pragma unroll
        for (int j = 0; j < 8; ++j)
            atomicAdd(&Mb[(size_t)(e0 + i) * 128 + (v0 + j)], acc[i][j] * KSCALE);
}

// ---------------------------------------------------------------------------
// Kernel 3: out[row][v] = sum_e qp[row][e] * M[batch(row)][e][v]
// grid = 256 blocks (64-row tiles over 16384 rows); same tiling as kernel 1, K=128.
// ---------------------------------------------------------------------------
__global__ __launch_bounds__(256) void qm_kernel(
    const float* __restrict__ qp, const float* __restrict__ M, float* __restrict__ out)
{
    const int tid   = threadIdx.x;
    const int row0  = blockIdx.x * 64;
    const int batch = row0 >> 11;                 // /2048
    const float* Mb = M + (size_t)batch * DQK * DV;

    __shared__ __align__(16) float Xs[16][68];
    __shared__ __align__(16) float Ws[16][128];

    const int trow = tid >> 5;
    const int tcol = tid & 31;
    const int r0   = trow * 8;
    const int c0   = tcol * 4;

    const int lxr = tid >> 2;
    const int lxk = (tid & 3) * 4;
    const int lwk = tid >> 5;
    const int lwc = (tid & 31) * 4;

    float acc[8][4];
    #pragma unroll
    for (int i = 0; i < 8; ++i)
        #pragma unroll
        for (int j = 0; j < 4; ++j) acc[i][j] = 0.f;

    for (int kc = 0; kc < 128; kc += 16) {
        float4 xv  = *(const float4*)&qp[(size_t)(row0 + lxr) * 128 + kc + lxk];
        float4 wv0 = *(const float4*)&Mb[(size_t)(kc + lwk) * 128 + lwc];
        float4 wv1 = *(const float4*)&Mb[(size_t)(kc + 8 + lwk) * 128 + lwc];
        __syncthreads();
        Xs[lxk + 0][lxr] = xv.x;
        Xs[lxk + 1][lxr] = xv.y;
        Xs[lxk + 2][lxr] = xv.z;
        Xs[lxk + 3][lxr] = xv.w;
        *(float4*)&Ws[lwk][lwc]     = wv0;
        *(float4*)&Ws[lwk + 8][lwc] = wv1;
        __syncthreads();
        #pragma unroll
        for (int kk = 0; kk < 16; ++kk) {
            float4 a0 = *(const float4*)&Xs[kk][r0];
            float4 a1 = *(const float4*)&Xs[kk][r0 + 4];
            float4 bb = *(const float4*)&Ws[kk][c0];
            float a[8] = {a0.x, a0.y, a0.z, a0.w, a1.x, a1.y, a1.z, a1.w};
            float bv4[4] = {bb.x, bb.y, bb.z, bb.w};
            #pragma unroll
            for (int i = 0; i < 8; ++i)
                #pragma unroll
                for (int j = 0; j < 4; ++j)
                    acc[i][j] = fmaf(a[i], bv4[j], acc[i][j]);
        }
    }

    #pragma unroll
    for (int i = 0; i < 8; ++i) {
        float4 o;
        o.x = acc[i][0]; o.y = acc[i][1]; o.z = acc[i][2]; o.w = acc[i][3];
        *(float4*)&out[(size_t)(row0 + r0 + i) * 128 + c0] = o;
    }
}

// ---------------------------------------------------------------------------
extern "C" void kernel_launch(void* const* d_in, const int* in_sizes, int n_in,
                              void* d_out, int out_size, void* d_ws, size_t ws_size,
                              hipStream_t stream)
{
    const float* query = (const float*)d_in[0];
    const float* key   = (const float*)d_in[1];
    const float* value = (const float*)d_in[2];
    const float* Wq    = (const float*)d_in[3];
    const float* bq    = (const float*)d_in[4];
    const float* Wk    = (const float*)d_in[5];
    const float* bk    = (const float*)d_in[6];
    const float* Wv    = (const float*)d_in[7];
    const float* bv    = (const float*)d_in[8];
    float* out = (float*)d_out;

    float* qp = (float*)d_ws;                           // 16384*128
    float* kp = qp + (size_t)MROWS * DQK;               // 16384*128
    float* vp = kp + (size_t)MROWS * DQK;               // 16384*128
    float* Mm = vp + (size_t)MROWS * DV;                // 8*128*128

    hipMemsetAsync(Mm, 0, (size_t)NB * DQK * DV * sizeof(float), stream);

    dim3 blk(256);
    dim3 g1(MROWS / 64, 3);
    proj_kernel<<<g1, blk, 0, stream>>>(query, Wq, bq, key, Wk, bk, value, Wv, bv,
                                        qp, kp, vp);
    dim3 g2(LK / 128, NB);
    ktv_kernel<<<g2, blk, 0, stream>>>(kp, vp, Mm);
    qm_kernel<<<MROWS / 64, blk, 0, stream>>>(qp, Mm, out);
}

// Round 2
// 105.552 us; speedup vs baseline: 2.4574x; 2.4574x over previous
//
#include <hip/hip_runtime.h>

typedef __attribute__((ext_vector_type(8))) short short8;
typedef __attribute__((ext_vector_type(4))) float f32x4;

#define NB 8
#define LQ 2048
#define LK 2048
#define DIN 1024
#define MROWS (NB * LQ)   // 16384

static constexpr float KSCALE = 0.022097086912079608f; // 1/sqrt(2048)

__device__ __forceinline__ ushort f2bf(float f) {
    union { float f; unsigned int u; } v; v.f = f;
    unsigned int r = v.u + 0x7FFFu + ((v.u >> 16) & 1u);   // RNE
    return (ushort)(r >> 16);
}
__device__ __forceinline__ float bf2f(ushort u) {
    union { unsigned int u; float f; } v; v.u = ((unsigned int)u) << 16;
    return v.f;
}

// ---------------------------------------------------------------------------
// prep: Wt[p][n][k] = bf16(W_p[k][n])  (transpose+convert, LDS tiled)
// grid (16, 2, 3), block 256
// ---------------------------------------------------------------------------
__global__ __launch_bounds__(256) void prep_kernel(
    const float* __restrict__ Wq, const float* __restrict__ Wk,
    const float* __restrict__ Wv, ushort* __restrict__ Wt)
{
    const float* W = (blockIdx.z == 0) ? Wq : (blockIdx.z == 1) ? Wk : Wv;
    ushort* O = Wt + (size_t)blockIdx.z * 128 * 1024;
    const int k0 = blockIdx.x * 64, n0 = blockIdx.y * 64;
    __shared__ float tile[64][65];
    const int t = threadIdx.x;
    {
        const int r = t >> 4, c = (t & 15) * 4;
        #pragma unroll
        for (int i = 0; i < 4; ++i) {
            float4 v = *(const float4*)&W[(size_t)(k0 + r + i * 16) * 128 + n0 + c];
            tile[r + i * 16][c + 0] = v.x; tile[r + i * 16][c + 1] = v.y;
            tile[r + i * 16][c + 2] = v.z; tile[r + i * 16][c + 3] = v.w;
        }
    }
    __syncthreads();
    {
        const int n = t >> 2, kc = (t & 3) * 16;
        ushort tmp[16];
        #pragma unroll
        for (int j = 0; j < 16; ++j) tmp[j] = f2bf(tile[kc + j][n]);
        *(uint4*)&O[(size_t)(n0 + n) * 1024 + k0 + kc]     = *(uint4*)&tmp[0];
        *(uint4*)&O[(size_t)(n0 + n) * 1024 + k0 + kc + 8] = *(uint4*)&tmp[8];
    }
}

// ---------------------------------------------------------------------------
// proj: Y = bf16(relu(X[16384,1024] @ W + b)); MFMA bf16, fused f32->bf16 staging.
// grid (128, 3), block 256 (4 waves, 2x2 of 64x64), BK=64, LDS XOR-swizzled.
// ---------------------------------------------------------------------------
__global__ __launch_bounds__(256) void proj_kernel(
    const float* __restrict__ Xq, const float* __restrict__ bq,
    const float* __restrict__ Xk, const float* __restrict__ bk,
    const float* __restrict__ Xv, const float* __restrict__ bv,
    const ushort* __restrict__ Wt,
    ushort* __restrict__ qp, ushort* __restrict__ kp, ushort* __restrict__ vp)
{
    const int p = blockIdx.y;
    const float* X; const float* bias; ushort* Y;
    if (p == 0)      { X = Xq; bias = bq; Y = qp; }
    else if (p == 1) { X = Xk; bias = bk; Y = kp; }
    else             { X = Xv; bias = bv; Y = vp; }
    const ushort* W = Wt + (size_t)p * 128 * 1024;

    __shared__ __align__(16) ushort smem[16384];  // 32 KB: As[128][64] | Bs[128][64]
    ushort* As = smem;
    ushort* Bs = smem + 8192;

    const int tid  = threadIdx.x;
    const int lane = tid & 63;
    const int w    = tid >> 6;
    const int wr   = (w >> 1) * 64;
    const int wc   = (w & 1) * 64;
    const int row0 = blockIdx.x * 128;

    // staging mapping: 2 threads per row, halves of BK=64
    const int ra = tid >> 1;
    const int ah = (tid & 1) * 32;
    const float*  Xrow = X + (size_t)(row0 + ra) * DIN + ah;
    const ushort* Wrow = W + (size_t)ra * DIN + ah;
    const int sswz = (ra & 7) << 3;   // ushort-index swizzle == byte ^ ((r&7)<<4)

    const int col  = lane & 15;
    const int kgrp = (lane >> 4) * 8;
    const int fswz = (col & 7) << 3;

    f32x4 acc[4][4];
    #pragma unroll
    for (int mi = 0; mi < 4; ++mi)
        #pragma unroll
        for (int ni = 0; ni < 4; ++ni)
            acc[mi][ni] = (f32x4){0.f, 0.f, 0.f, 0.f};

    for (int kc = 0; kc < DIN; kc += 64) {
        float4 xa[8];
        uint4  wb[4];
        #pragma unroll
        for (int j = 0; j < 8; ++j) xa[j] = *(const float4*)&Xrow[kc + j * 4];
        #pragma unroll
        for (int j = 0; j < 4; ++j) wb[j] = *(const uint4*)&Wrow[kc + j * 8];

        __syncthreads();   // previous step's frag reads done
        #pragma unroll
        for (int j = 0; j < 8; ++j) {
            uint2 pk_;
            pk_.x = (unsigned)f2bf(xa[j].x) | ((unsigned)f2bf(xa[j].y) << 16);
            pk_.y = (unsigned)f2bf(xa[j].z) | ((unsigned)f2bf(xa[j].w) << 16);
            *(uint2*)&As[(ra * 64 + ah + j * 4) ^ sswz] = pk_;
        }
        #pragma unroll
        for (int j = 0; j < 4; ++j)
            *(uint4*)&Bs[(ra * 64 + ah + j * 8) ^ sswz] = wb[j];
        __syncthreads();

        #pragma unroll
        for (int kk = 0; kk < 2; ++kk) {
            const int kb = kk * 32 + kgrp;
            short8 af[4], bfv[4];
            #pragma unroll
            for (int mi = 0; mi < 4; ++mi)
                af[mi] = *(const short8*)&As[((wr + mi * 16 + col) * 64 + kb) ^ fswz];
            #pragma unroll
            for (int ni = 0; ni < 4; ++ni)
                bfv[ni] = *(const short8*)&Bs[((wc + ni * 16 + col) * 64 + kb) ^ fswz];
            #pragma unroll
            for (int mi = 0; mi < 4; ++mi)
                #pragma unroll
                for (int ni = 0; ni < 4; ++ni)
                    acc[mi][ni] = __builtin_amdgcn_mfma_f32_16x16x32_bf16(
                        af[mi], bfv[ni], acc[mi][ni], 0, 0, 0);
        }
    }

    float bb[4];
    #pragma unroll
    for (int ni = 0; ni < 4; ++ni) bb[ni] = bias[wc + ni * 16 + col];

    __syncthreads();                    // done with As/Bs; reuse as Ys[128][128]
    const int orow = (lane >> 4) * 4;
    #pragma unroll
    for (int mi = 0; mi < 4; ++mi)
        #pragma unroll
        for (int ni = 0; ni < 4; ++ni)
            #pragma unroll
            for (int j = 0; j < 4; ++j) {
                float v = fmaxf(acc[mi][ni][j] + bb[ni], 0.f);
                const int rl = wr + mi * 16 + orow + j;
                const int cl = wc + ni * 16 + col;
                smem[(rl * 128 + cl) ^ ((rl & 15) << 3)] = f2bf(v);
            }
    __syncthreads();

    const int crow = tid >> 1;
    const int chh  = (tid & 1) * 64;
    ushort* Yg = Y + (size_t)(row0 + crow) * 128 + chh;
    const int cswz = (crow & 15) << 3;
    #pragma unroll
    for (int j = 0; j < 8; ++j)
        *(uint4*)&Yg[j * 8] = *(const uint4*)&smem[(crow * 128 + chh + j * 8) ^ cswz];
}

// ---------------------------------------------------------------------------
// ktv: per (batch, 64-row chunk): partial Mt_part[v][e] = sum_r v[r][v]*k[r][e]
// written as bf16 (no atomics). grid (32, 8), block 256.
// ---------------------------------------------------------------------------
__global__ __launch_bounds__(256) void ktv_kernel(
    const ushort* __restrict__ kp, const ushort* __restrict__ vp,
    ushort* __restrict__ part)
{
    const int b = blockIdx.y, chunk = blockIdx.x;
    const ushort* K = kp + ((size_t)b * LK + chunk * 64) * 128;
    const ushort* V = vp + ((size_t)b * LK + chunk * 64) * 128;
    ushort* P = part + ((size_t)(b * 32 + chunk)) * 16384;

    __shared__ __align__(16) ushort ks[64 * 128];
    __shared__ __align__(16) ushort vs[64 * 128];
    const int t = threadIdx.x;
    {
        const int r = t >> 2, cc = (t & 3) * 32;
        #pragma unroll
        for (int j = 0; j < 4; ++j) {
            *(uint4*)&ks[r * 128 + cc + j * 8] = *(const uint4*)&K[r * 128 + cc + j * 8];
            *(uint4*)&vs[r * 128 + cc + j * 8] = *(const uint4*)&V[r * 128 + cc + j * 8];
        }
    }
    __syncthreads();

    const int e0 = (t & 15) * 8;      // lane-contiguous in e (coalesced stores)
    const int v0 = (t >> 4) * 8;
    float acc[8][8];                  // [vi][ej]
    #pragma unroll
    for (int i = 0; i < 8; ++i)
        #pragma unroll
        for (int j = 0; j < 8; ++j) acc[i][j] = 0.f;

    for (int r = 0; r < 64; ++r) {
        uint4 kf = *(const uint4*)&ks[r * 128 + e0];
        uint4 vf = *(const uint4*)&vs[r * 128 + v0];
        const ushort* kw = (const ushort*)&kf;
        const ushort* vw = (const ushort*)&vf;
        float ke[8], ve[8];
        #pragma unroll
        for (int j = 0; j < 8; ++j) { ke[j] = bf2f(kw[j]); ve[j] = bf2f(vw[j]); }
        #pragma unroll
        for (int i = 0; i < 8; ++i)
            #pragma unroll
            for (int j = 0; j < 8; ++j)
                acc[i][j] = fmaf(ve[i], ke[j], acc[i][j]);
    }

    #pragma unroll
    for (int i = 0; i < 8; ++i) {
        ushort tmp[8];
        #pragma unroll
        for (int j = 0; j < 8; ++j) tmp[j] = f2bf(acc[i][j]);
        *(uint4*)&P[(v0 + i) * 128 + e0] = *(uint4*)&tmp[0];
    }
}

// ---------------------------------------------------------------------------
// reduce: Mt[b][v*128+e] = bf16(KSCALE * sum_{c<32} part[b][c][v*128+e])
// grid 512, block 256
// ---------------------------------------------------------------------------
__global__ __launch_bounds__(256) void reduce_kernel(
    const ushort* __restrict__ part, ushort* __restrict__ Mt)
{
    const int g = blockIdx.x * 256 + threadIdx.x;       // 8*16384
    const int b = g >> 14, idx = g & 16383;
    const ushort* P = part + (size_t)b * 32 * 16384 + idx;
    float s = 0.f;
    #pragma unroll
    for (int c = 0; c < 32; ++c) s += bf2f(P[(size_t)c * 16384]);
    Mt[g] = f2bf(s * KSCALE);
}

// ---------------------------------------------------------------------------
// qm: out[row][v] = sum_e qp[row][e] * Mt[b][v][e]   (MFMA, single K=128)
// grid 256, block 256 (4 waves, each 64x32 of the 64x128 tile)
// ---------------------------------------------------------------------------
__global__ __launch_bounds__(256) void qm_kernel(
    const ushort* __restrict__ qp, const ushort* __restrict__ Mt,
    float* __restrict__ out)
{
    const int row0 = blockIdx.x * 64;
    const int b = row0 >> 11;
    const ushort* Q = qp + (size_t)row0 * 128;
    const ushort* M = Mt + (size_t)b * 16384;

    __shared__ __align__(16) ushort As[64 * 128];
    __shared__ __align__(16) ushort Bs[128 * 128];

    const int t = threadIdx.x;
    {
        const int r = t >> 2, cc = (t & 3) * 32;
        const int swz = (r & 15) << 3;
        #pragma unroll
        for (int j = 0; j < 4; ++j)
            *(uint4*)&As[(r * 128 + cc + j * 8) ^ swz] = *(const uint4*)&Q[r * 128 + cc + j * 8];
    }
    {
        const int r = t >> 1, cc = (t & 1) * 64;
        const int swz = (r & 15) << 3;
        #pragma unroll
        for (int j = 0; j < 8; ++j)
            *(uint4*)&Bs[(r * 128 + cc + j * 8) ^ swz] = *(const uint4*)&M[r * 128 + cc + j * 8];
    }
    __syncthreads();

    const int lane = t & 63;
    const int wcol = (t >> 6) * 32;
    const int col  = lane & 15;
    const int kgrp = (lane >> 4) * 8;
    const int fswz = col << 3;

    f32x4 acc[4][2];
    #pragma unroll
    for (int mi = 0; mi < 4; ++mi)
        #pragma unroll
        for (int ni = 0; ni < 2; ++ni)
            acc[mi][ni] = (f32x4){0.f, 0.f, 0.f, 0.f};

    #pragma unroll
    for (int kk = 0; kk < 4; ++kk) {
        const int kb = kk * 32 + kgrp;
        short8 af[4], bfv[2];
        #pragma unroll
        for (int mi = 0; mi < 4; ++mi)
            af[mi] = *(const short8*)&As[((mi * 16 + col) * 128 + kb) ^ fswz];
        #pragma unroll
        for (int ni = 0; ni < 2; ++ni)
            bfv[ni] = *(const short8*)&Bs[((wcol + ni * 16 + col) * 128 + kb) ^ fswz];
        #pragma unroll
        for (int mi = 0; mi < 4; ++mi)
            #pragma unroll
            for (int ni = 0; ni < 2; ++ni)
                acc[mi][ni] = __builtin_amdgcn_mfma_f32_16x16x32_bf16(
                    af[mi], bfv[ni], acc[mi][ni], 0, 0, 0);
    }

    const int orow = (lane >> 4) * 4;
    #pragma unroll
    for (int mi = 0; mi < 4; ++mi)
        #pragma unroll
        for (int ni = 0; ni < 2; ++ni)
            #pragma unroll
            for (int j = 0; j < 4; ++j)
                out[(size_t)(row0 + mi * 16 + orow + j) * 128 + wcol + ni * 16 + col] =
                    acc[mi][ni][j];
}

// ---------------------------------------------------------------------------
extern "C" void kernel_launch(void* const* d_in, const int* in_sizes, int n_in,
                              void* d_out, int out_size, void* d_ws, size_t ws_size,
                              hipStream_t stream)
{
    const float* query = (const float*)d_in[0];
    const float* key   = (const float*)d_in[1];
    const float* value = (const float*)d_in[2];
    const float* Wq    = (const float*)d_in[3];
    const float* bq    = (const float*)d_in[4];
    const float* Wk    = (const float*)d_in[5];
    const float* bk    = (const float*)d_in[6];
    const float* Wv    = (const float*)d_in[7];
    const float* bv    = (const float*)d_in[8];
    float* out = (float*)d_out;

    ushort* qp   = (ushort*)d_ws;                    // 16384*128 bf16 (4 MB)
    ushort* kp   = qp + (size_t)MROWS * 128;         // 4 MB
    ushort* vp   = kp + (size_t)MROWS * 128;         // 4 MB
    ushort* Wt   = vp + (size_t)MROWS * 128;         // 3*128*1024 bf16 (768 KB)
    ushort* part = Wt + (size_t)3 * 128 * 1024;      // 8*32*16384 bf16 (8 MB)
    ushort* Mt   = part + (size_t)8 * 32 * 16384;    // 8*16384 bf16 (256 KB)

    dim3 blk(256);
    prep_kernel<<<dim3(16, 2, 3), blk, 0, stream>>>(Wq, Wk, Wv, Wt);
    proj_kernel<<<dim3(128, 3), blk, 0, stream>>>(query, bq, key, bk, value, bv,
                                                  Wt, qp, kp, vp);
    ktv_kernel<<<dim3(32, NB), blk, 0, stream>>>(kp, vp, part);
    reduce_kernel<<<512, blk, 0, stream>>>(part, Mt);
    qm_kernel<<<MROWS / 64, blk, 0, stream>>>(qp, Mt, out);
}